// Round 1
// baseline (602.543 us; speedup 1.0000x reference)
//
#include <hip/hip_runtime.h>

// NetVLAD: N=64, HW=1024, D=512, K=64, fp32.
// Pass A: s = x@W+b per pixel, softmax -> a [N*HW, K]; block-reduced a_sum[n,k].
// Pass B: v[n,d,k] = sum_hw x[n,hw,d]*a[n,hw,k] + a_sum[n,k]*C[d,k].
// Pass C: intra-norm over d per (n,k), then global L2 per n.

#define EPSF 1e-12f

// ---------------- Kernel A: assignment GEMM + softmax ----------------
// grid 1024 blocks (64 pixels each), 256 threads; 4 pixels x 4 k per thread.
__global__ __launch_bounds__(256) void kassign(
    const float* __restrict__ x, const float* __restrict__ Wm,
    const float* __restrict__ b, float* __restrict__ a,
    float* __restrict__ a_sum) {
  const int p0 = blockIdx.x * 64;
  const int n = p0 >> 10;
  const int t = threadIdx.x;
  const int tx = t & 15;   // k-group: k = tx*4 + kk
  const int ty = t >> 4;   // pixel-group: p = p0 + ty*4 + pp
  __shared__ float xs[64][65];   // [pixel][d] padded -> conflict-free column reads
  __shared__ float ws[64][64];   // [d][k]
  __shared__ float asum_s[64];
  if (t < 64) asum_s[t] = 0.f;

  float4 bk = *(const float4*)&b[tx * 4];
  float acc[4][4];
#pragma unroll
  for (int pp = 0; pp < 4; ++pp) {
    acc[pp][0] = bk.x; acc[pp][1] = bk.y; acc[pp][2] = bk.z; acc[pp][3] = bk.w;
  }

  for (int dt = 0; dt < 512; dt += 64) {
    __syncthreads();
#pragma unroll
    for (int r = 0; r < 16; ++r) {
      int idx = r * 256 + t;
      int i = idx >> 6, j = idx & 63;
      xs[i][j] = x[(size_t)(p0 + i) * 512 + dt + j];
      ws[i][j] = Wm[(size_t)(dt + i) * 64 + j];
    }
    __syncthreads();
#pragma unroll 16
    for (int d = 0; d < 64; ++d) {
      float4 wr = *(const float4*)&ws[d][tx * 4];
      float x0 = xs[ty * 4 + 0][d];
      float x1 = xs[ty * 4 + 1][d];
      float x2 = xs[ty * 4 + 2][d];
      float x3 = xs[ty * 4 + 3][d];
      acc[0][0] += x0 * wr.x; acc[0][1] += x0 * wr.y; acc[0][2] += x0 * wr.z; acc[0][3] += x0 * wr.w;
      acc[1][0] += x1 * wr.x; acc[1][1] += x1 * wr.y; acc[1][2] += x1 * wr.z; acc[1][3] += x1 * wr.w;
      acc[2][0] += x2 * wr.x; acc[2][1] += x2 * wr.y; acc[2][2] += x2 * wr.z; acc[2][3] += x2 * wr.w;
      acc[3][0] += x3 * wr.x; acc[3][1] += x3 * wr.y; acc[3][2] += x3 * wr.z; acc[3][3] += x3 * wr.w;
    }
  }

  // Softmax over k (64 values spread across 16 lanes x 4 regs, lanes tx=0..15
  // of the same ty group are contiguous within a wave -> shfl_xor width 16).
  float lsum[4] = {0.f, 0.f, 0.f, 0.f};
#pragma unroll
  for (int pp = 0; pp < 4; ++pp) {
    float m = fmaxf(fmaxf(acc[pp][0], acc[pp][1]), fmaxf(acc[pp][2], acc[pp][3]));
#pragma unroll
    for (int msk = 1; msk < 16; msk <<= 1) m = fmaxf(m, __shfl_xor(m, msk, 64));
    float e0 = __expf(acc[pp][0] - m);
    float e1 = __expf(acc[pp][1] - m);
    float e2 = __expf(acc[pp][2] - m);
    float e3 = __expf(acc[pp][3] - m);
    float s = e0 + e1 + e2 + e3;
#pragma unroll
    for (int msk = 1; msk < 16; msk <<= 1) s += __shfl_xor(s, msk, 64);
    float inv = 1.0f / s;
    float4 av;
    av.x = e0 * inv; av.y = e1 * inv; av.z = e2 * inv; av.w = e3 * inv;
    *(float4*)&a[(size_t)(p0 + ty * 4 + pp) * 64 + tx * 4] = av;
    lsum[0] += av.x; lsum[1] += av.y; lsum[2] += av.z; lsum[3] += av.w;
  }

  __syncthreads();
#pragma unroll
  for (int kk = 0; kk < 4; ++kk) atomicAdd(&asum_s[tx * 4 + kk], lsum[kk]);
  __syncthreads();
  if (t < 64) atomicAdd(&a_sum[n * 64 + t], asum_s[t]);
}

// ---------------- Kernel B: VLAD GEMM (x^T @ a per image) + centers --------
// grid (D/64, N), 256 threads; 4 d x 4 k per thread, hw tiled by 32.
__global__ __launch_bounds__(256) void kvlad(
    const float* __restrict__ x, const float* __restrict__ a,
    const float* __restrict__ a_sum, const float* __restrict__ C,
    float* __restrict__ v) {
  const int d0 = blockIdx.x * 64;
  const int n = blockIdx.y;
  const int t = threadIdx.x;
  const int tx = t & 15;   // k-group
  const int ty = t >> 4;   // d-group
  __shared__ float xs[32][64];  // [hw][d]
  __shared__ float as[32][64];  // [hw][k]
  float acc[4][4] = {{0.f}};
  const float* xb = x + (size_t)n * 1024 * 512;
  const float* ab = a + (size_t)n * 1024 * 64;

  for (int h0 = 0; h0 < 1024; h0 += 32) {
    __syncthreads();
#pragma unroll
    for (int r = 0; r < 8; ++r) {
      int idx = r * 256 + t;
      int i = idx >> 6, j = idx & 63;
      xs[i][j] = xb[(size_t)(h0 + i) * 512 + d0 + j];
      as[i][j] = ab[(size_t)(h0 + i) * 64 + j];
    }
    __syncthreads();
#pragma unroll 8
    for (int i = 0; i < 32; ++i) {
      float4 xr = *(const float4*)&xs[i][ty * 4];
      float4 ar = *(const float4*)&as[i][tx * 4];
      acc[0][0] += xr.x * ar.x; acc[0][1] += xr.x * ar.y; acc[0][2] += xr.x * ar.z; acc[0][3] += xr.x * ar.w;
      acc[1][0] += xr.y * ar.x; acc[1][1] += xr.y * ar.y; acc[1][2] += xr.y * ar.z; acc[1][3] += xr.y * ar.w;
      acc[2][0] += xr.z * ar.x; acc[2][1] += xr.z * ar.y; acc[2][2] += xr.z * ar.z; acc[2][3] += xr.z * ar.w;
      acc[3][0] += xr.w * ar.x; acc[3][1] += xr.w * ar.y; acc[3][2] += xr.w * ar.z; acc[3][3] += xr.w * ar.w;
    }
  }

  float4 asv = *(const float4*)&a_sum[n * 64 + tx * 4];
#pragma unroll
  for (int dd = 0; dd < 4; ++dd) {
    int d = d0 + ty * 4 + dd;
    float4 cv = *(const float4*)&C[(size_t)d * 64 + tx * 4];
    float4 o;
    o.x = acc[dd][0] + asv.x * cv.x;
    o.y = acc[dd][1] + asv.y * cv.y;
    o.z = acc[dd][2] + asv.z * cv.z;
    o.w = acc[dd][3] + asv.w * cv.w;
    *(float4*)&v[(size_t)n * 32768 + (size_t)d * 64 + tx * 4] = o;
  }
}

// ---------------- Kernel C: intra-norm + final L2 ----------------
// grid 64 (one block per image), 1024 threads.
__global__ __launch_bounds__(1024) void knorm(
    const float* __restrict__ v, float* __restrict__ out) {
  const int n = blockIdx.x;
  const int t = threadIdx.x;
  const int k = t & 63;
  const int dg = t >> 6;  // 0..15
  const float* vn = v + (size_t)n * 32768;

  float ssq = 0.f;
  for (int d = dg; d < 512; d += 16) {
    float val = vn[d * 64 + k];
    ssq += val * val;
  }
  __shared__ float red[64];
  __shared__ float invk[64];
  __shared__ float tots;
  if (t < 64) red[t] = 0.f;
  __syncthreads();
  atomicAdd(&red[k], ssq);
  __syncthreads();
  if (t < 64) {
    float c = red[t];
    invk[t] = rsqrtf(c + EPSF);
    float contrib = c / (c + EPSF);  // = sum over d of intra-normalized^2
#pragma unroll
    for (int m = 32; m; m >>= 1) contrib += __shfl_xor(contrib, m, 64);
    if (t == 0) tots = rsqrtf(contrib + EPSF);
  }
  __syncthreads();
  const float ts = tots;
  const float ik = invk[k];
  for (int d = dg; d < 512; d += 16) {
    int idx = d * 64 + k;
    out[(size_t)n * 32768 + idx] = vn[idx] * ik * ts;
  }
}

extern "C" void kernel_launch(void* const* d_in, const int* in_sizes, int n_in,
                              void* d_out, int out_size, void* d_ws, size_t ws_size,
                              hipStream_t stream) {
  const float* x  = (const float*)d_in[0];   // [64,32,32,512]
  const float* Wm = (const float*)d_in[1];   // [512,64]
  const float* b  = (const float*)d_in[2];   // [64]
  const float* C  = (const float*)d_in[3];   // [512,64]
  float* out = (float*)d_out;                // [64, 32768]

  float* a     = (float*)d_ws;                   // 64*1024*64 floats = 16 MiB
  float* v     = a + (size_t)64 * 1024 * 64;     // 64*512*64 floats = 8 MiB
  float* a_sum = v + (size_t)64 * 512 * 64;      // 4096 floats

  hipMemsetAsync(a_sum, 0, 4096 * sizeof(float), stream);
  kassign<<<dim3(1024), dim3(256), 0, stream>>>(x, Wm, b, a, a_sum);
  kvlad<<<dim3(8, 64), dim3(256), 0, stream>>>(x, a, a_sum, C, v);
  knorm<<<dim3(64), dim3(1024), 0, stream>>>(v, out);
}

// Round 2
// 278.053 us; speedup vs baseline: 2.1670x; 2.1670x over previous
//
#include <hip/hip_runtime.h>

// NetVLAD fp32, N=64 HW=1024 D=512 K=64, via bf16 split-precision MFMA.
// x = x_hi + x_lo (bf16 RNE + bf16 residual); products use
// hi*hi + lo*hi + hi*lo  -> ~2^-17 relative error, effectively fp32.

#define EPSF 1e-12f

typedef short bf16x8 __attribute__((ext_vector_type(8)));
typedef float f32x16 __attribute__((ext_vector_type(16)));

__device__ inline unsigned short f2bf_rne(float f) {
  union { float f; unsigned u; } v; v.f = f;
  unsigned u = v.u;
  unsigned r = u + 0x7fffu + ((u >> 16) & 1u);
  return (unsigned short)(r >> 16);
}
__device__ inline float bf2f(unsigned short h) {
  union { unsigned u; float f; } v; v.u = ((unsigned)h) << 16;
  return v.f;
}

// ---------------- K0: W[512][64] -> Wt_hi/Wt_lo [64][512] bf16 ----------------
__global__ __launch_bounds__(256) void kprep(
    const float* __restrict__ Wm,
    unsigned short* __restrict__ wt_hi, unsigned short* __restrict__ wt_lo) {
  __shared__ float tile[64][65];
  const int t = threadIdx.x, bx = blockIdx.x;  // 8 blocks, 64 d-rows each
  {
    int col = (t & 15) * 4, rbase = t >> 4;
#pragma unroll
    for (int r = 0; r < 4; ++r) {
      int row = rbase + 16 * r;
      *(float4*)&tile[row][col] =
          *(const float4*)&Wm[(size_t)(bx * 64 + row) * 64 + col];
    }
  }
  __syncthreads();
  int k = t >> 2, seg = (t & 3) * 16;
  size_t o = (size_t)k * 512 + bx * 64 + seg;
#pragma unroll
  for (int j = 0; j < 16; j += 2) {
    float f0 = tile[seg + j][k], f1 = tile[seg + j + 1][k];
    unsigned short h0 = f2bf_rne(f0), h1 = f2bf_rne(f1);
    unsigned short l0 = f2bf_rne(f0 - bf2f(h0)), l1 = f2bf_rne(f1 - bf2f(h1));
    *(unsigned*)&wt_hi[o + j] = (unsigned)h0 | ((unsigned)h1 << 16);
    *(unsigned*)&wt_lo[o + j] = (unsigned)l0 | ((unsigned)l1 << 16);
  }
}

// ---------------- Kernel A: assign GEMM (MFMA) + softmax + a^T + a_sum -------
// 512 blocks, 256 thr / 4 waves. Block: 128 pixels x 64 K. Wave: 32 pixels.
__global__ __launch_bounds__(256) void kassign(
    const float* __restrict__ x,
    const unsigned short* __restrict__ wt_hi,
    const unsigned short* __restrict__ wt_lo,
    const float* __restrict__ b,
    unsigned short* __restrict__ at_hi, unsigned short* __restrict__ at_lo,
    float* __restrict__ a_sum) {
  __shared__ unsigned short xs_hi[128][72];
  __shared__ unsigned short xs_lo[128][72];
  __shared__ unsigned short ws_hi[64][72];
  __shared__ unsigned short ws_lo[64][72];
  const int t = threadIdx.x;
  const int w = t >> 6, lane = t & 63, l31 = lane & 31, h = lane >> 5;
  const int p0 = blockIdx.x * 128;

  f32x16 acc0, acc1;
#pragma unroll
  for (int i = 0; i < 16; ++i) { acc0[i] = 0.f; acc1[i] = 0.f; }

  for (int c = 0; c < 8; ++c) {
    const int dc = c * 64;
    __syncthreads();
    // stage x chunk [128 p][64 d] -> bf16 hi/lo
    {
      int col = (t & 15) * 4, rbase = t >> 4;
#pragma unroll
      for (int r = 0; r < 8; ++r) {
        int row = rbase + 16 * r;
        float4 xv = *(const float4*)&x[(size_t)(p0 + row) * 512 + dc + col];
        unsigned short h0 = f2bf_rne(xv.x), h1 = f2bf_rne(xv.y);
        unsigned short h2 = f2bf_rne(xv.z), h3 = f2bf_rne(xv.w);
        unsigned short l0 = f2bf_rne(xv.x - bf2f(h0)), l1 = f2bf_rne(xv.y - bf2f(h1));
        unsigned short l2 = f2bf_rne(xv.z - bf2f(h2)), l3 = f2bf_rne(xv.w - bf2f(h3));
        uint2 ph, pl;
        ph.x = (unsigned)h0 | ((unsigned)h1 << 16); ph.y = (unsigned)h2 | ((unsigned)h3 << 16);
        pl.x = (unsigned)l0 | ((unsigned)l1 << 16); pl.y = (unsigned)l2 | ((unsigned)l3 << 16);
        *(uint2*)&xs_hi[row][col] = ph;
        *(uint2*)&xs_lo[row][col] = pl;
      }
    }
    // stage W chunk [64 k][64 d] bf16 (already converted)
    {
      int k = t >> 2, seg = (t & 3) * 16;
      size_t g = (size_t)k * 512 + dc + seg;
      *(uint4*)&ws_hi[k][seg] = *(const uint4*)&wt_hi[g];
      *(uint4*)&ws_hi[k][seg + 8] = *(const uint4*)&wt_hi[g + 8];
      *(uint4*)&ws_lo[k][seg] = *(const uint4*)&wt_lo[g];
      *(uint4*)&ws_lo[k][seg + 8] = *(const uint4*)&wt_lo[g + 8];
    }
    __syncthreads();
#pragma unroll
    for (int s = 0; s < 4; ++s) {
      int kd = s * 16 + h * 8;
      bf16x8 axh = *(const bf16x8*)&xs_hi[32 * w + l31][kd];
      bf16x8 axl = *(const bf16x8*)&xs_lo[32 * w + l31][kd];
      bf16x8 b0h = *(const bf16x8*)&ws_hi[l31][kd];
      bf16x8 b0l = *(const bf16x8*)&ws_lo[l31][kd];
      bf16x8 b1h = *(const bf16x8*)&ws_hi[32 + l31][kd];
      bf16x8 b1l = *(const bf16x8*)&ws_lo[32 + l31][kd];
      acc0 = __builtin_amdgcn_mfma_f32_32x32x16_bf16(axh, b0h, acc0, 0, 0, 0);
      acc0 = __builtin_amdgcn_mfma_f32_32x32x16_bf16(axl, b0h, acc0, 0, 0, 0);
      acc0 = __builtin_amdgcn_mfma_f32_32x32x16_bf16(axh, b0l, acc0, 0, 0, 0);
      acc1 = __builtin_amdgcn_mfma_f32_32x32x16_bf16(axh, b1h, acc1, 0, 0, 0);
      acc1 = __builtin_amdgcn_mfma_f32_32x32x16_bf16(axl, b1h, acc1, 0, 0, 0);
      acc1 = __builtin_amdgcn_mfma_f32_32x32x16_bf16(axh, b1l, acc1, 0, 0, 0);
    }
  }

  // epilogue: bias + softmax (per pixel = per C/D row), emit a^T bf16 hi/lo
  const float bias0 = b[l31], bias1 = b[32 + l31];
  float a0[16], a1[16];
  float sum0 = 0.f, sum1 = 0.f;
#pragma unroll
  for (int r = 0; r < 16; ++r) {
    float s0 = acc0[r] + bias0, s1 = acc1[r] + bias1;
    float m = fmaxf(s0, s1);
#pragma unroll
    for (int msk = 1; msk < 32; msk <<= 1) m = fmaxf(m, __shfl_xor(m, msk, 64));
    float e0 = __expf(s0 - m), e1 = __expf(s1 - m);
    float S = e0 + e1;
#pragma unroll
    for (int msk = 1; msk < 32; msk <<= 1) S += __shfl_xor(S, msk, 64);
    float inv = 1.0f / S;
    a0[r] = e0 * inv; a1[r] = e1 * inv;
    sum0 += a0[r]; sum1 += a1[r];
  }
  const int n = p0 >> 10;
  const int hwb = (p0 & 1023) + 32 * w + 4 * h;
  const size_t kb0 = ((size_t)n * 64 + l31) * 1024;
  const size_t kb1 = ((size_t)n * 64 + 32 + l31) * 1024;
#pragma unroll
  for (int g = 0; g < 4; ++g) {
    int hw = hwb + 8 * g;
    unsigned short vh[8], vl[8];
#pragma unroll
    for (int j = 0; j < 4; ++j) {
      unsigned short hh = f2bf_rne(a0[4 * g + j]);
      vh[j] = hh; vl[j] = f2bf_rne(a0[4 * g + j] - bf2f(hh));
      unsigned short hh1 = f2bf_rne(a1[4 * g + j]);
      vh[4 + j] = hh1; vl[4 + j] = f2bf_rne(a1[4 * g + j] - bf2f(hh1));
    }
    uint2 u;
    u.x = (unsigned)vh[0] | ((unsigned)vh[1] << 16); u.y = (unsigned)vh[2] | ((unsigned)vh[3] << 16);
    *(uint2*)&at_hi[kb0 + hw] = u;
    u.x = (unsigned)vl[0] | ((unsigned)vl[1] << 16); u.y = (unsigned)vl[2] | ((unsigned)vl[3] << 16);
    *(uint2*)&at_lo[kb0 + hw] = u;
    u.x = (unsigned)vh[4] | ((unsigned)vh[5] << 16); u.y = (unsigned)vh[6] | ((unsigned)vh[7] << 16);
    *(uint2*)&at_hi[kb1 + hw] = u;
    u.x = (unsigned)vl[4] | ((unsigned)vl[5] << 16); u.y = (unsigned)vl[6] | ((unsigned)vl[7] << 16);
    *(uint2*)&at_lo[kb1 + hw] = u;
  }
  sum0 += __shfl_xor(sum0, 32, 64);
  sum1 += __shfl_xor(sum1, 32, 64);
  if (lane < 32) {
    atomicAdd(&a_sum[n * 64 + l31], sum0);
    atomicAdd(&a_sum[n * 64 + 32 + l31], sum1);
  }
}

// ---------------- Kernel B: v = x^T @ a (MFMA over hw) + a_sum*C -> d_out ----
// grid (8 d-tiles, 64 images), 256 thr / 4 waves. Wave: 32d x 32k tile.
__global__ __launch_bounds__(256) void kvlad(
    const float* __restrict__ x,
    const unsigned short* __restrict__ at_hi,
    const unsigned short* __restrict__ at_lo,
    const float* __restrict__ a_sum, const float* __restrict__ C,
    float* __restrict__ out) {
  __shared__ float xs[64][68];             // [hw][d] fp32
  __shared__ unsigned short ash[64][72];   // [k][hw] bf16 hi
  __shared__ unsigned short asl[64][72];   // [k][hw] bf16 lo
  const int t = threadIdx.x;
  const int w = t >> 6, lane = t & 63, l31 = lane & 31, h = lane >> 5;
  const int n = blockIdx.y, d0 = blockIdx.x * 64;
  const int dw = 32 * (w & 1);   // wave d sub-tile
  const int kw = 32 * (w >> 1);  // wave k sub-tile
  const float* xb = x + (size_t)n * 1024 * 512;

  f32x16 acc;
#pragma unroll
  for (int i = 0; i < 16; ++i) acc[i] = 0.f;

  for (int c = 0; c < 16; ++c) {
    const int hw0 = c * 64;
    __syncthreads();
    {
      int col = (t & 15) * 4, rbase = t >> 4;
#pragma unroll
      for (int r = 0; r < 4; ++r) {
        int row = rbase + 16 * r;
        *(float4*)&xs[row][col] =
            *(const float4*)&xb[(size_t)(hw0 + row) * 512 + d0 + col];
      }
    }
    {
      int k = t >> 2, seg = (t & 3) * 16;
      size_t g = ((size_t)n * 64 + k) * 1024 + hw0 + seg;
      *(uint4*)&ash[k][seg] = *(const uint4*)&at_hi[g];
      *(uint4*)&ash[k][seg + 8] = *(const uint4*)&at_hi[g + 8];
      *(uint4*)&asl[k][seg] = *(const uint4*)&at_lo[g];
      *(uint4*)&asl[k][seg + 8] = *(const uint4*)&at_lo[g + 8];
    }
    __syncthreads();
#pragma unroll
    for (int s = 0; s < 4; ++s) {
      int kk = s * 16 + h * 8;  // hw offset within chunk
      bf16x8 axh, axl;
#pragma unroll
      for (int j = 0; j < 8; ++j) {
        float f = xs[kk + j][dw + l31];
        unsigned short hi = f2bf_rne(f);
        axh[j] = (short)hi;
        axl[j] = (short)f2bf_rne(f - bf2f(hi));
      }
      bf16x8 bh = *(const bf16x8*)&ash[kw + l31][kk];
      bf16x8 bl = *(const bf16x8*)&asl[kw + l31][kk];
      acc = __builtin_amdgcn_mfma_f32_32x32x16_bf16(axh, bh, acc, 0, 0, 0);
      acc = __builtin_amdgcn_mfma_f32_32x32x16_bf16(axl, bh, acc, 0, 0, 0);
      acc = __builtin_amdgcn_mfma_f32_32x32x16_bf16(axh, bl, acc, 0, 0, 0);
    }
  }
  const float as = a_sum[n * 64 + kw + l31];
#pragma unroll
  for (int r = 0; r < 16; ++r) {
    int row = (r & 3) + 8 * (r >> 2) + 4 * h;
    int d = d0 + dw + row;
    float cv = C[(size_t)d * 64 + kw + l31];
    out[((size_t)n * 512 + d) * 64 + kw + l31] = acc[r] + as * cv;
  }
}

// ---------------- C1: ssq[n][k] over d ----------------
__global__ __launch_bounds__(256) void kssq(
    const float* __restrict__ out, float* __restrict__ ssq) {
  const int n = blockIdx.y, slice = blockIdx.x;
  const int t = threadIdx.x, k = t & 63, rg = t >> 6;
  const float* vb = out + (size_t)n * 32768 + (size_t)slice * 4096;
  float s = 0.f;
#pragma unroll
  for (int r = rg; r < 64; r += 4) { float v = vb[r * 64 + k]; s += v * v; }
  __shared__ float red[64];
  if (t < 64) red[t] = 0.f;
  __syncthreads();
  atomicAdd(&red[k], s);
  __syncthreads();
  if (t < 64) atomicAdd(&ssq[n * 64 + t], red[t]);
}

// ---------------- C3: scale in place ----------------
__global__ __launch_bounds__(256) void kscale(
    float* __restrict__ out, const float* __restrict__ ssq) {
  const int n = blockIdx.y, slice = blockIdx.x;
  const int t = threadIdx.x, k = t & 63, rg = t >> 6;
  __shared__ float sk[64];
  __shared__ float tot;
  if (t < 64) {
    float c = ssq[n * 64 + t];
    sk[t] = rsqrtf(c + EPSF);
    float contrib = c / (c + EPSF);
#pragma unroll
    for (int m = 32; m; m >>= 1) contrib += __shfl_xor(contrib, m, 64);
    if (t == 0) tot = rsqrtf(contrib + EPSF);
  }
  __syncthreads();
  const float scale = sk[k] * tot;
  float* vb = out + (size_t)n * 32768 + (size_t)slice * 4096;
#pragma unroll
  for (int r = rg; r < 64; r += 4) vb[r * 64 + k] *= scale;
}

extern "C" void kernel_launch(void* const* d_in, const int* in_sizes, int n_in,
                              void* d_out, int out_size, void* d_ws, size_t ws_size,
                              hipStream_t stream) {
  const float* x  = (const float*)d_in[0];   // [64,32,32,512]
  const float* Wm = (const float*)d_in[1];   // [512,64]
  const float* b  = (const float*)d_in[2];   // [64]
  const float* C  = (const float*)d_in[3];   // [512,64]
  float* out = (float*)d_out;                // [64, 32768]

  unsigned short* at_hi = (unsigned short*)d_ws;           // 8 MiB
  unsigned short* at_lo = at_hi + (size_t)64 * 64 * 1024;  // 8 MiB
  unsigned short* wt_hi = at_lo + (size_t)64 * 64 * 1024;  // 64 KiB
  unsigned short* wt_lo = wt_hi + (size_t)64 * 512;        // 64 KiB
  float* a_sum = (float*)(wt_lo + (size_t)64 * 512);       // 16 KiB
  float* ssq   = a_sum + 4096;                             // 16 KiB

  hipMemsetAsync(a_sum, 0, 8192 * sizeof(float), stream);  // a_sum + ssq
  kprep<<<dim3(8), dim3(256), 0, stream>>>(Wm, wt_hi, wt_lo);
  kassign<<<dim3(512), dim3(256), 0, stream>>>(x, wt_hi, wt_lo, b, at_hi, at_lo, a_sum);
  kvlad<<<dim3(8, 64), dim3(256), 0, stream>>>(x, at_hi, at_lo, a_sum, C, out);
  kssq<<<dim3(8, 64), dim3(256), 0, stream>>>(out, ssq);
  kscale<<<dim3(8, 64), dim3(256), 0, stream>>>(out, ssq);
}

// Round 3
// 274.389 us; speedup vs baseline: 2.1959x; 1.0134x over previous
//
#include <hip/hip_runtime.h>

// NetVLAD fp32, N=64 HW=1024 D=512 K=64. Plain-bf16 MFMA (error budget:
// bf16 rounding adds ~3e-5 abs to the 1.2e-4 fp32-vs-ref floor; thr 6e-4).
// R3: hi-only bf16 + register-prefetch double buffering + fused ssq.

#define EPSF 1e-12f

typedef short bf16x8 __attribute__((ext_vector_type(8)));
typedef float f32x16 __attribute__((ext_vector_type(16)));

__device__ inline unsigned short f2bf_rne(float f) {
  union { float f; unsigned u; } v; v.f = f;
  unsigned u = v.u;
  unsigned r = u + 0x7fffu + ((u >> 16) & 1u);
  return (unsigned short)(r >> 16);
}
__device__ inline unsigned pk2(float a, float b) {
  return (unsigned)f2bf_rne(a) | ((unsigned)f2bf_rne(b) << 16);
}

// ---------------- K0: W[512][64] -> Wt [64 k][512 d] bf16 ----------------
__global__ __launch_bounds__(256) void kprep(
    const float* __restrict__ Wm, unsigned short* __restrict__ wt) {
  __shared__ float tile[64][65];
  const int t = threadIdx.x, bx = blockIdx.x;  // 8 blocks, 64 d-rows each
  {
    int col = (t & 15) * 4, rbase = t >> 4;
#pragma unroll
    for (int r = 0; r < 4; ++r) {
      int row = rbase + 16 * r;
      *(float4*)&tile[row][col] =
          *(const float4*)&Wm[(size_t)(bx * 64 + row) * 64 + col];
    }
  }
  __syncthreads();
  int k = t >> 2, seg = (t & 3) * 16;
  size_t o = (size_t)k * 512 + bx * 64 + seg;
#pragma unroll
  for (int j = 0; j < 16; j += 2)
    *(unsigned*)&wt[o + j] = pk2(tile[seg + j][k], tile[seg + j + 1][k]);
}

// ---------------- Kernel A: assign GEMM + softmax -> a^T bf16, a_sum -------
// 512 blocks, 256 thr / 4 waves. Block: 128 pixels x 64 K.
__global__ __launch_bounds__(256) void kassign(
    const float* __restrict__ x, const unsigned short* __restrict__ wt,
    const float* __restrict__ b, unsigned short* __restrict__ at,
    float* __restrict__ a_sum) {
  __shared__ unsigned short xs[128][72];
  __shared__ unsigned short ws[64][72];
  const int t = threadIdx.x;
  const int w = t >> 6, lane = t & 63, l31 = lane & 31, h = lane >> 5;
  const int p0 = blockIdx.x * 128;
  const int col = (t & 15) * 4, rbase = t >> 4;     // x stage map
  const int wk = t >> 2, wseg = (t & 3) * 16;       // W stage map

  // prefetch chunk 0
  float4 px[8];
  uint4 pw0, pw1;
#pragma unroll
  for (int r = 0; r < 8; ++r)
    px[r] = *(const float4*)&x[(size_t)(p0 + rbase + 16 * r) * 512 + col];
  pw0 = *(const uint4*)&wt[(size_t)wk * 512 + wseg];
  pw1 = *(const uint4*)&wt[(size_t)wk * 512 + wseg + 8];

  f32x16 acc0, acc1;
#pragma unroll
  for (int i = 0; i < 16; ++i) { acc0[i] = 0.f; acc1[i] = 0.f; }

  for (int c = 0; c < 8; ++c) {
    __syncthreads();
#pragma unroll
    for (int r = 0; r < 8; ++r) {
      uint2 ph;
      ph.x = pk2(px[r].x, px[r].y);
      ph.y = pk2(px[r].z, px[r].w);
      *(uint2*)&xs[rbase + 16 * r][col] = ph;
    }
    *(uint4*)&ws[wk][wseg] = pw0;
    *(uint4*)&ws[wk][wseg + 8] = pw1;
    __syncthreads();
    if (c < 7) {
      const int dc = (c + 1) * 64;
#pragma unroll
      for (int r = 0; r < 8; ++r)
        px[r] = *(const float4*)&x[(size_t)(p0 + rbase + 16 * r) * 512 + dc + col];
      pw0 = *(const uint4*)&wt[(size_t)wk * 512 + dc + wseg];
      pw1 = *(const uint4*)&wt[(size_t)wk * 512 + dc + wseg + 8];
    }
#pragma unroll
    for (int s = 0; s < 4; ++s) {
      int kd = s * 16 + h * 8;
      bf16x8 ax = *(const bf16x8*)&xs[32 * w + l31][kd];
      bf16x8 b0 = *(const bf16x8*)&ws[l31][kd];
      bf16x8 b1 = *(const bf16x8*)&ws[32 + l31][kd];
      acc0 = __builtin_amdgcn_mfma_f32_32x32x16_bf16(ax, b0, acc0, 0, 0, 0);
      acc1 = __builtin_amdgcn_mfma_f32_32x32x16_bf16(ax, b1, acc1, 0, 0, 0);
    }
  }

  // epilogue: bias + softmax per pixel row, emit a^T bf16, a_sum
  const float bias0 = b[l31], bias1 = b[32 + l31];
  float a0[16], a1[16];
  float sum0 = 0.f, sum1 = 0.f;
#pragma unroll
  for (int r = 0; r < 16; ++r) {
    float s0 = acc0[r] + bias0, s1 = acc1[r] + bias1;
    float m = fmaxf(s0, s1);
#pragma unroll
    for (int msk = 1; msk < 32; msk <<= 1) m = fmaxf(m, __shfl_xor(m, msk, 64));
    float e0 = __expf(s0 - m), e1 = __expf(s1 - m);
    float S = e0 + e1;
#pragma unroll
    for (int msk = 1; msk < 32; msk <<= 1) S += __shfl_xor(S, msk, 64);
    float inv = 1.0f / S;
    a0[r] = e0 * inv; a1[r] = e1 * inv;
    sum0 += a0[r]; sum1 += a1[r];
  }
  const int n = p0 >> 10;
  const int hwb = (p0 & 1023) + 32 * w + 4 * h;
  const size_t kb0 = ((size_t)n * 64 + l31) * 1024;
  const size_t kb1 = ((size_t)n * 64 + 32 + l31) * 1024;
#pragma unroll
  for (int g = 0; g < 4; ++g) {
    int hw = hwb + 8 * g;
    uint2 u;
    u.x = pk2(a0[4 * g + 0], a0[4 * g + 1]);
    u.y = pk2(a0[4 * g + 2], a0[4 * g + 3]);
    *(uint2*)&at[kb0 + hw] = u;
    u.x = pk2(a1[4 * g + 0], a1[4 * g + 1]);
    u.y = pk2(a1[4 * g + 2], a1[4 * g + 3]);
    *(uint2*)&at[kb1 + hw] = u;
  }
  sum0 += __shfl_xor(sum0, 32, 64);
  sum1 += __shfl_xor(sum1, 32, 64);
  if (lane < 32) {
    atomicAdd(&a_sum[n * 64 + l31], sum0);
    atomicAdd(&a_sum[n * 64 + 32 + l31], sum1);
  }
}

// ---------------- Kernel B: v = x^T @ a + a_sum*C -> out, fused ssq --------
// grid (8 d-tiles, 64 images), 256 thr / 4 waves. Wave: 32d x 32k.
__global__ __launch_bounds__(256) void kvlad(
    const float* __restrict__ x, const unsigned short* __restrict__ at,
    const float* __restrict__ a_sum, const float* __restrict__ C,
    float* __restrict__ out, float* __restrict__ ssq) {
  __shared__ float xs[64][68];             // [hw][d] fp32
  __shared__ unsigned short as_[64][72];   // [k][hw] bf16
  const int t = threadIdx.x;
  const int w = t >> 6, lane = t & 63, l31 = lane & 31, h = lane >> 5;
  const int n = blockIdx.y, d0 = blockIdx.x * 64;
  const int dw = 32 * (w & 1), kw = 32 * (w >> 1);
  const float* xb = x + (size_t)n * 1024 * 512;
  const int col = (t & 15) * 4, rbase = t >> 4;   // x stage map
  const int ak = t >> 2, aseg = (t & 3) * 16;     // at stage map
  const size_t abase = ((size_t)n * 64 + ak) * 1024;

  float4 px[4];
  uint4 pa0, pa1;
#pragma unroll
  for (int r = 0; r < 4; ++r)
    px[r] = *(const float4*)&xb[(size_t)(rbase + 16 * r) * 512 + d0 + col];
  pa0 = *(const uint4*)&at[abase + aseg];
  pa1 = *(const uint4*)&at[abase + aseg + 8];

  f32x16 acc;
#pragma unroll
  for (int i = 0; i < 16; ++i) acc[i] = 0.f;

  for (int c = 0; c < 16; ++c) {
    __syncthreads();
#pragma unroll
    for (int r = 0; r < 4; ++r)
      *(float4*)&xs[rbase + 16 * r][col] = px[r];
    *(uint4*)&as_[ak][aseg] = pa0;
    *(uint4*)&as_[ak][aseg + 8] = pa1;
    __syncthreads();
    if (c < 15) {
      const int hw0 = (c + 1) * 64;
#pragma unroll
      for (int r = 0; r < 4; ++r)
        px[r] = *(const float4*)&xb[(size_t)(hw0 + rbase + 16 * r) * 512 + d0 + col];
      pa0 = *(const uint4*)&at[abase + hw0 + aseg];
      pa1 = *(const uint4*)&at[abase + hw0 + aseg + 8];
    }
#pragma unroll
    for (int s = 0; s < 4; ++s) {
      int kk = s * 16 + h * 8;  // hw offset within chunk
      bf16x8 ax;
#pragma unroll
      for (int j = 0; j < 8; ++j)
        ax[j] = (short)f2bf_rne(xs[kk + j][dw + l31]);
      bf16x8 bh = *(const bf16x8*)&as_[kw + l31][kk];
      acc = __builtin_amdgcn_mfma_f32_32x32x16_bf16(ax, bh, acc, 0, 0, 0);
    }
  }

  const int k = kw + l31;
  const float as = a_sum[n * 64 + k];
  float sq = 0.f;
#pragma unroll
  for (int r = 0; r < 16; ++r) {
    int row = (r & 3) + 8 * (r >> 2) + 4 * h;
    int d = d0 + dw + row;
    float o = acc[r] + as * C[(size_t)d * 64 + k];
    out[((size_t)n * 512 + d) * 64 + k] = o;
    sq += o * o;
  }
  atomicAdd(&ssq[n * 64 + k], sq);
}

// ---------------- C: scale in place ----------------
__global__ __launch_bounds__(256) void kscale(
    float* __restrict__ out, const float* __restrict__ ssq) {
  const int n = blockIdx.y, slice = blockIdx.x;
  const int t = threadIdx.x, k = t & 63, rg = t >> 6;
  __shared__ float sk[64];
  __shared__ float tot;
  if (t < 64) {
    float c = ssq[n * 64 + t];
    sk[t] = rsqrtf(c + EPSF);
    float contrib = c / (c + EPSF);
#pragma unroll
    for (int m = 32; m; m >>= 1) contrib += __shfl_xor(contrib, m, 64);
    if (t == 0) tot = rsqrtf(contrib + EPSF);
  }
  __syncthreads();
  const float scale = sk[k] * tot;
  float* vb = out + (size_t)n * 32768 + (size_t)slice * 4096;
#pragma unroll
  for (int r = rg; r < 64; r += 4) vb[r * 64 + k] *= scale;
}

extern "C" void kernel_launch(void* const* d_in, const int* in_sizes, int n_in,
                              void* d_out, int out_size, void* d_ws, size_t ws_size,
                              hipStream_t stream) {
  const float* x  = (const float*)d_in[0];   // [64,32,32,512]
  const float* Wm = (const float*)d_in[1];   // [512,64]
  const float* b  = (const float*)d_in[2];   // [64]
  const float* C  = (const float*)d_in[3];   // [512,64]
  float* out = (float*)d_out;                // [64, 32768]

  unsigned short* at = (unsigned short*)d_ws;          // 8 MiB [n*64+k][1024 hw]
  unsigned short* wt = at + (size_t)64 * 64 * 1024;    // 64 KiB [k][512 d]
  float* a_sum = (float*)(wt + (size_t)64 * 512);      // 16 KiB
  float* ssq   = a_sum + 4096;                         // 16 KiB

  hipMemsetAsync(a_sum, 0, 8192 * sizeof(float), stream);  // a_sum + ssq
  kprep<<<dim3(8), dim3(256), 0, stream>>>(Wm, wt);
  kassign<<<dim3(512), dim3(256), 0, stream>>>(x, wt, b, at, a_sum);
  kvlad<<<dim3(8, 64), dim3(256), 0, stream>>>(x, at, a_sum, C, out, ssq);
  kscale<<<dim3(8, 64), dim3(256), 0, stream>>>(out, ssq);
}

// Round 4
// 260.353 us; speedup vs baseline: 2.3143x; 1.0539x over previous
//
#include <hip/hip_runtime.h>

// NetVLAD fp32, N=64 HW=1024 D=512 K=64. bf16 MFMA.
// R4: kconv pass produces xt[n][d][hw] bf16 so kvlad's A-fragments are
// contiguous ds_read_b128 (no per-element LDS gather / convert in the loop).

#define EPSF 1e-12f

typedef short bf16x8 __attribute__((ext_vector_type(8)));
typedef float f32x16 __attribute__((ext_vector_type(16)));

__device__ inline unsigned short f2bf_rne(float f) {
  union { float f; unsigned u; } v; v.f = f;
  unsigned u = v.u;
  unsigned r = u + 0x7fffu + ((u >> 16) & 1u);
  return (unsigned short)(r >> 16);
}
__device__ inline unsigned pk2(float a, float b) {
  return (unsigned)f2bf_rne(a) | ((unsigned)f2bf_rne(b) << 16);
}

// ---------------- K0: W[512][64] -> Wt [64 k][512 d] bf16 ----------------
__global__ __launch_bounds__(256) void kprep(
    const float* __restrict__ Wm, unsigned short* __restrict__ wt) {
  __shared__ float tile[64][65];
  const int t = threadIdx.x, bx = blockIdx.x;  // 8 blocks, 64 d-rows each
  {
    int col = (t & 15) * 4, rbase = t >> 4;
#pragma unroll
    for (int r = 0; r < 4; ++r) {
      int row = rbase + 16 * r;
      *(float4*)&tile[row][col] =
          *(const float4*)&Wm[(size_t)(bx * 64 + row) * 64 + col];
    }
  }
  __syncthreads();
  int k = t >> 2, seg = (t & 3) * 16;
  size_t o = (size_t)k * 512 + bx * 64 + seg;
#pragma unroll
  for (int j = 0; j < 16; j += 2)
    *(unsigned*)&wt[o + j] = pk2(tile[seg + j][k], tile[seg + j + 1][k]);
}

// ---------------- K1: x[n][hw][d] fp32 -> xt[n][d][hw] bf16 ----------------
// grid (128, 64): bx = hw-tile(16) | d-tile(8). 64x64 tile per block.
__global__ __launch_bounds__(256) void kconv(
    const float* __restrict__ x, unsigned short* __restrict__ xt) {
  __shared__ unsigned short td[64][66];  // [hw][d], 66 breaks column-read banks
  const int t = threadIdx.x;
  const int hw0 = (blockIdx.x & 15) * 64, d0 = (blockIdx.x >> 4) * 64;
  const int n = blockIdx.y;
  {
    int c = (t & 15) * 4, r0 = t >> 4;
#pragma unroll
    for (int rr = 0; rr < 4; ++rr) {
      int row = r0 + 16 * rr;
      float4 v = *(const float4*)&x[((size_t)(n * 1024 + hw0 + row)) * 512 + d0 + c];
      *(unsigned*)&td[row][c] = pk2(v.x, v.y);
      *(unsigned*)&td[row][c + 2] = pk2(v.z, v.w);
    }
  }
  __syncthreads();
  const int d = t >> 2, hs = (t & 3) * 16;
  unsigned o[8];
#pragma unroll
  for (int j = 0; j < 8; ++j)
    o[j] = (unsigned)td[hs + 2 * j][d] | ((unsigned)td[hs + 2 * j + 1][d] << 16);
  size_t g = ((size_t)n * 512 + d0 + d) * 1024 + hw0 + hs;
  *(uint4*)&xt[g] = *(uint4*)&o[0];
  *(uint4*)&xt[g + 8] = *(uint4*)&o[4];
}

// ---------------- Kernel A: assign GEMM + softmax -> a^T bf16, a_sum -------
// 512 blocks, 256 thr / 4 waves. Block: 128 pixels x 64 K.
__global__ __launch_bounds__(256) void kassign(
    const float* __restrict__ x, const unsigned short* __restrict__ wt,
    const float* __restrict__ b, unsigned short* __restrict__ at,
    float* __restrict__ a_sum) {
  __shared__ unsigned short xs[128][72];
  __shared__ unsigned short ws[64][72];
  const int t = threadIdx.x;
  const int w = t >> 6, lane = t & 63, l31 = lane & 31, h = lane >> 5;
  const int p0 = blockIdx.x * 128;
  const int col = (t & 15) * 4, rbase = t >> 4;     // x stage map
  const int wk = t >> 2, wseg = (t & 3) * 16;       // W stage map

  float4 px[8];
  uint4 pw0, pw1;
#pragma unroll
  for (int r = 0; r < 8; ++r)
    px[r] = *(const float4*)&x[(size_t)(p0 + rbase + 16 * r) * 512 + col];
  pw0 = *(const uint4*)&wt[(size_t)wk * 512 + wseg];
  pw1 = *(const uint4*)&wt[(size_t)wk * 512 + wseg + 8];

  f32x16 acc0, acc1;
#pragma unroll
  for (int i = 0; i < 16; ++i) { acc0[i] = 0.f; acc1[i] = 0.f; }

  for (int c = 0; c < 8; ++c) {
    __syncthreads();
#pragma unroll
    for (int r = 0; r < 8; ++r) {
      uint2 ph;
      ph.x = pk2(px[r].x, px[r].y);
      ph.y = pk2(px[r].z, px[r].w);
      *(uint2*)&xs[rbase + 16 * r][col] = ph;
    }
    *(uint4*)&ws[wk][wseg] = pw0;
    *(uint4*)&ws[wk][wseg + 8] = pw1;
    __syncthreads();
    if (c < 7) {
      const int dc = (c + 1) * 64;
#pragma unroll
      for (int r = 0; r < 8; ++r)
        px[r] = *(const float4*)&x[(size_t)(p0 + rbase + 16 * r) * 512 + dc + col];
      pw0 = *(const uint4*)&wt[(size_t)wk * 512 + dc + wseg];
      pw1 = *(const uint4*)&wt[(size_t)wk * 512 + dc + wseg + 8];
    }
#pragma unroll
    for (int s = 0; s < 4; ++s) {
      int kd = s * 16 + h * 8;
      bf16x8 ax = *(const bf16x8*)&xs[32 * w + l31][kd];
      bf16x8 b0 = *(const bf16x8*)&ws[l31][kd];
      bf16x8 b1 = *(const bf16x8*)&ws[32 + l31][kd];
      acc0 = __builtin_amdgcn_mfma_f32_32x32x16_bf16(ax, b0, acc0, 0, 0, 0);
      acc1 = __builtin_amdgcn_mfma_f32_32x32x16_bf16(ax, b1, acc1, 0, 0, 0);
    }
  }

  const float bias0 = b[l31], bias1 = b[32 + l31];
  float a0[16], a1[16];
  float sum0 = 0.f, sum1 = 0.f;
#pragma unroll
  for (int r = 0; r < 16; ++r) {
    float s0 = acc0[r] + bias0, s1 = acc1[r] + bias1;
    float m = fmaxf(s0, s1);
#pragma unroll
    for (int msk = 1; msk < 32; msk <<= 1) m = fmaxf(m, __shfl_xor(m, msk, 64));
    float e0 = __expf(s0 - m), e1 = __expf(s1 - m);
    float S = e0 + e1;
#pragma unroll
    for (int msk = 1; msk < 32; msk <<= 1) S += __shfl_xor(S, msk, 64);
    float inv = 1.0f / S;
    a0[r] = e0 * inv; a1[r] = e1 * inv;
    sum0 += a0[r]; sum1 += a1[r];
  }
  const int n = p0 >> 10;
  const int hwb = (p0 & 1023) + 32 * w + 4 * h;
  const size_t kb0 = ((size_t)n * 64 + l31) * 1024;
  const size_t kb1 = ((size_t)n * 64 + 32 + l31) * 1024;
#pragma unroll
  for (int g = 0; g < 4; ++g) {
    int hw = hwb + 8 * g;
    uint2 u;
    u.x = pk2(a0[4 * g + 0], a0[4 * g + 1]);
    u.y = pk2(a0[4 * g + 2], a0[4 * g + 3]);
    *(uint2*)&at[kb0 + hw] = u;
    u.x = pk2(a1[4 * g + 0], a1[4 * g + 1]);
    u.y = pk2(a1[4 * g + 2], a1[4 * g + 3]);
    *(uint2*)&at[kb1 + hw] = u;
  }
  sum0 += __shfl_xor(sum0, 32, 64);
  sum1 += __shfl_xor(sum1, 32, 64);
  if (lane < 32) {
    atomicAdd(&a_sum[n * 64 + l31], sum0);
    atomicAdd(&a_sum[n * 64 + 32 + l31], sum1);
  }
}

// ---------------- Kernel B: v = xt @ a^T + a_sum*C -> out, fused ssq -------
// grid (8 d-tiles, 64 images), 256 thr / 4 waves. Wave: 32d x 32k.
// Pure-b128 inner loop: A from xt[d][hw] bf16, B from at[k][hw] bf16.
__global__ __launch_bounds__(256) void kvlad(
    const unsigned short* __restrict__ xt, const unsigned short* __restrict__ at,
    const float* __restrict__ a_sum, const float* __restrict__ C,
    float* __restrict__ out, float* __restrict__ ssq) {
  __shared__ unsigned short xa[64][72];    // [d][hw-chunk]
  __shared__ unsigned short as_[64][72];   // [k][hw-chunk]
  const int t = threadIdx.x;
  const int w = t >> 6, lane = t & 63, l31 = lane & 31, h = lane >> 5;
  const int n = blockIdx.y, d0 = blockIdx.x * 64;
  const int dw = 32 * (w & 1), kw = 32 * (w >> 1);
  const int sd = t >> 2, sseg = (t & 3) * 16;  // stage maps (both operands)
  const size_t xbase = ((size_t)n * 512 + d0 + sd) * 1024;
  const size_t abase = ((size_t)n * 64 + sd) * 1024;

  uint4 px0, px1, pa0, pa1;
  px0 = *(const uint4*)&xt[xbase + sseg];
  px1 = *(const uint4*)&xt[xbase + sseg + 8];
  pa0 = *(const uint4*)&at[abase + sseg];
  pa1 = *(const uint4*)&at[abase + sseg + 8];

  f32x16 acc;
#pragma unroll
  for (int i = 0; i < 16; ++i) acc[i] = 0.f;

  for (int c = 0; c < 16; ++c) {
    __syncthreads();
    *(uint4*)&xa[sd][sseg] = px0;
    *(uint4*)&xa[sd][sseg + 8] = px1;
    *(uint4*)&as_[sd][sseg] = pa0;
    *(uint4*)&as_[sd][sseg + 8] = pa1;
    __syncthreads();
    if (c < 15) {
      const int hw0 = (c + 1) * 64;
      px0 = *(const uint4*)&xt[xbase + hw0 + sseg];
      px1 = *(const uint4*)&xt[xbase + hw0 + sseg + 8];
      pa0 = *(const uint4*)&at[abase + hw0 + sseg];
      pa1 = *(const uint4*)&at[abase + hw0 + sseg + 8];
    }
#pragma unroll
    for (int s = 0; s < 4; ++s) {
      int kk = s * 16 + h * 8;  // hw offset within chunk
      bf16x8 ax = *(const bf16x8*)&xa[dw + l31][kk];
      bf16x8 bb = *(const bf16x8*)&as_[kw + l31][kk];
      acc = __builtin_amdgcn_mfma_f32_32x32x16_bf16(ax, bb, acc, 0, 0, 0);
    }
  }

  const int k = kw + l31;
  const float as = a_sum[n * 64 + k];
  float sq = 0.f;
#pragma unroll
  for (int r = 0; r < 16; ++r) {
    int row = (r & 3) + 8 * (r >> 2) + 4 * h;
    int d = d0 + dw + row;
    float o = acc[r] + as * C[(size_t)d * 64 + k];
    out[((size_t)n * 512 + d) * 64 + k] = o;
    sq += o * o;
  }
  atomicAdd(&ssq[n * 64 + k], sq);
}

// ---------------- C: scale in place ----------------
__global__ __launch_bounds__(256) void kscale(
    float* __restrict__ out, const float* __restrict__ ssq) {
  const int n = blockIdx.y, slice = blockIdx.x;
  const int t = threadIdx.x, k = t & 63, rg = t >> 6;
  __shared__ float sk[64];
  __shared__ float tot;
  if (t < 64) {
    float c = ssq[n * 64 + t];
    sk[t] = rsqrtf(c + EPSF);
    float contrib = c / (c + EPSF);
#pragma unroll
    for (int m = 32; m; m >>= 1) contrib += __shfl_xor(contrib, m, 64);
    if (t == 0) tot = rsqrtf(contrib + EPSF);
  }
  __syncthreads();
  const float scale = sk[k] * tot;
  float* vb = out + (size_t)n * 32768 + (size_t)slice * 4096;
#pragma unroll
  for (int r = rg; r < 64; r += 4) vb[r * 64 + k] *= scale;
}

extern "C" void kernel_launch(void* const* d_in, const int* in_sizes, int n_in,
                              void* d_out, int out_size, void* d_ws, size_t ws_size,
                              hipStream_t stream) {
  const float* x  = (const float*)d_in[0];   // [64,32,32,512]
  const float* Wm = (const float*)d_in[1];   // [512,64]
  const float* b  = (const float*)d_in[2];   // [64]
  const float* C  = (const float*)d_in[3];   // [512,64]
  float* out = (float*)d_out;                // [64, 32768]

  unsigned short* at = (unsigned short*)d_ws;          // 8 MiB  [n*64+k][1024]
  unsigned short* xt = at + (size_t)64 * 64 * 1024;    // 64 MiB [n][512 d][1024 hw]
  unsigned short* wt = xt + (size_t)64 * 512 * 1024;   // 64 KiB [k][512 d]
  float* a_sum = (float*)(wt + (size_t)64 * 512);      // 16 KiB
  float* ssq   = a_sum + 4096;                         // 16 KiB

  hipMemsetAsync(a_sum, 0, 8192 * sizeof(float), stream);  // a_sum + ssq
  kprep<<<dim3(8), dim3(256), 0, stream>>>(Wm, wt);
  kconv<<<dim3(128, 64), dim3(256), 0, stream>>>(x, xt);
  kassign<<<dim3(512), dim3(256), 0, stream>>>(x, wt, b, at, a_sum);
  kvlad<<<dim3(8, 64), dim3(256), 0, stream>>>(xt, at, a_sum, C, out, ssq);
  kscale<<<dim3(8, 64), dim3(256), 0, stream>>>(out, ssq);
}

// Round 5
// 246.261 us; speedup vs baseline: 2.4468x; 1.0572x over previous
//
#include <hip/hip_runtime.h>

// NetVLAD fp32, N=64 HW=1024 D=512 K=64. bf16 MFMA.
// R5: hw packed cvt (v_cvt_pk_bf16_f32) + kconv fused into kassign
// (kassign emits both xs LDS tile and the xt[n][d][hw] bf16 global slab).

#define EPSF 1e-12f

typedef short bf16x8 __attribute__((ext_vector_type(8)));
typedef float f32x16 __attribute__((ext_vector_type(16)));

__device__ inline unsigned short f2bf_rne(float f) {
  union { float f; unsigned u; } v; v.f = f;
  unsigned u = v.u;
  unsigned r = u + 0x7fffu + ((u >> 16) & 1u);
  return (unsigned short)(r >> 16);
}
__device__ inline unsigned pk2(float a, float b) {
#if __has_builtin(__builtin_amdgcn_cvt_pk_bf16_f32)
  auto r = __builtin_amdgcn_cvt_pk_bf16_f32(a, b);
  return __builtin_bit_cast(unsigned, r);
#else
  return (unsigned)f2bf_rne(a) | ((unsigned)f2bf_rne(b) << 16);
#endif
}

// ---------------- K0: W[512][64] -> Wt [64 k][512 d] bf16 ----------------
__global__ __launch_bounds__(256) void kprep(
    const float* __restrict__ Wm, unsigned short* __restrict__ wt) {
  __shared__ float tile[64][65];
  const int t = threadIdx.x, bx = blockIdx.x;  // 8 blocks, 64 d-rows each
  {
    int col = (t & 15) * 4, rbase = t >> 4;
#pragma unroll
    for (int r = 0; r < 4; ++r) {
      int row = rbase + 16 * r;
      *(float4*)&tile[row][col] =
          *(const float4*)&Wm[(size_t)(bx * 64 + row) * 64 + col];
    }
  }
  __syncthreads();
  int k = t >> 2, seg = (t & 3) * 16;
  size_t o = (size_t)k * 512 + bx * 64 + seg;
#pragma unroll
  for (int j = 0; j < 16; j += 2)
    *(unsigned*)&wt[o + j] = pk2(tile[seg + j][k], tile[seg + j + 1][k]);
}

// ---------------- Kernel A: assign GEMM + softmax -> at, xt, a_sum ---------
// 512 blocks, 256 thr / 4 waves. Block: 128 pixels x 64 K.
// Staging map: thread t -> pixels q*8..q*8+7 (q=t>>4), d-cols c4..c4+3
// (c4=(t&15)*4). Each chunk also emits the transposed xt[d][hw] slab.
__global__ __launch_bounds__(256) void kassign(
    const float* __restrict__ x, const unsigned short* __restrict__ wt,
    const float* __restrict__ b, unsigned short* __restrict__ at,
    unsigned short* __restrict__ xt, float* __restrict__ a_sum) {
  __shared__ unsigned short xs[128][72];
  __shared__ unsigned short ws[64][72];
  const int t = threadIdx.x;
  const int w = t >> 6, lane = t & 63, l31 = lane & 31, h = lane >> 5;
  const int p0 = blockIdx.x * 128;
  const int n = p0 >> 10;
  const int hwbase = p0 & 1023;
  const int q8 = (t >> 4) * 8, c4 = (t & 15) * 4;  // x stage map
  const int wk = t >> 2, wseg = (t & 3) * 16;      // W stage map

  // prefetch chunk 0
  float4 px[8];
  uint4 pw0, pw1;
#pragma unroll
  for (int j = 0; j < 8; ++j)
    px[j] = *(const float4*)&x[(size_t)(p0 + q8 + j) * 512 + c4];
  pw0 = *(const uint4*)&wt[(size_t)wk * 512 + wseg];
  pw1 = *(const uint4*)&wt[(size_t)wk * 512 + wseg + 8];

  f32x16 acc0, acc1;
#pragma unroll
  for (int i = 0; i < 16; ++i) { acc0[i] = 0.f; acc1[i] = 0.f; }

  for (int c = 0; c < 8; ++c) {
    const int dc = c * 64;
    __syncthreads();
    // LDS xs tile [p][d] bf16
#pragma unroll
    for (int j = 0; j < 8; ++j) {
      uint2 ph;
      ph.x = pk2(px[j].x, px[j].y);
      ph.y = pk2(px[j].z, px[j].w);
      *(uint2*)&xs[q8 + j][c4] = ph;
    }
    *(uint4*)&ws[wk][wseg] = pw0;
    *(uint4*)&ws[wk][wseg + 8] = pw1;
    // xt slab: for each of my 4 d values, 8 hw-contiguous bf16
    {
      const float* p = (const float*)px;  // px[j][i] = p[4j+i]
#pragma unroll
      for (int i = 0; i < 4; ++i) {
        uint4 o;
        o.x = pk2(px[0][i], px[1][i]);
        o.y = pk2(px[2][i], px[3][i]);
        o.z = pk2(px[4][i], px[5][i]);
        o.w = pk2(px[6][i], px[7][i]);
        *(uint4*)&xt[((size_t)n * 512 + dc + c4 + i) * 1024 + hwbase + q8] = o;
      }
      (void)p;
    }
    __syncthreads();
    if (c < 7) {
      const int dn = (c + 1) * 64;
#pragma unroll
      for (int j = 0; j < 8; ++j)
        px[j] = *(const float4*)&x[(size_t)(p0 + q8 + j) * 512 + dn + c4];
      pw0 = *(const uint4*)&wt[(size_t)wk * 512 + dn + wseg];
      pw1 = *(const uint4*)&wt[(size_t)wk * 512 + dn + wseg + 8];
    }
#pragma unroll
    for (int s = 0; s < 4; ++s) {
      int kd = s * 16 + h * 8;
      bf16x8 ax = *(const bf16x8*)&xs[32 * w + l31][kd];
      bf16x8 b0 = *(const bf16x8*)&ws[l31][kd];
      bf16x8 b1 = *(const bf16x8*)&ws[32 + l31][kd];
      acc0 = __builtin_amdgcn_mfma_f32_32x32x16_bf16(ax, b0, acc0, 0, 0, 0);
      acc1 = __builtin_amdgcn_mfma_f32_32x32x16_bf16(ax, b1, acc1, 0, 0, 0);
    }
  }

  // epilogue: bias + softmax per pixel row, emit a^T bf16, a_sum
  const float bias0 = b[l31], bias1 = b[32 + l31];
  float a0[16], a1[16];
  float sum0 = 0.f, sum1 = 0.f;
#pragma unroll
  for (int r = 0; r < 16; ++r) {
    float s0 = acc0[r] + bias0, s1 = acc1[r] + bias1;
    float m = fmaxf(s0, s1);
#pragma unroll
    for (int msk = 1; msk < 32; msk <<= 1) m = fmaxf(m, __shfl_xor(m, msk, 64));
    float e0 = __expf(s0 - m), e1 = __expf(s1 - m);
    float S = e0 + e1;
#pragma unroll
    for (int msk = 1; msk < 32; msk <<= 1) S += __shfl_xor(S, msk, 64);
    float inv = 1.0f / S;
    a0[r] = e0 * inv; a1[r] = e1 * inv;
    sum0 += a0[r]; sum1 += a1[r];
  }
  const int hwb = hwbase + 32 * w + 4 * h;
  const size_t kb0 = ((size_t)n * 64 + l31) * 1024;
  const size_t kb1 = ((size_t)n * 64 + 32 + l31) * 1024;
#pragma unroll
  for (int g = 0; g < 4; ++g) {
    int hw = hwb + 8 * g;
    uint2 u;
    u.x = pk2(a0[4 * g + 0], a0[4 * g + 1]);
    u.y = pk2(a0[4 * g + 2], a0[4 * g + 3]);
    *(uint2*)&at[kb0 + hw] = u;
    u.x = pk2(a1[4 * g + 0], a1[4 * g + 1]);
    u.y = pk2(a1[4 * g + 2], a1[4 * g + 3]);
    *(uint2*)&at[kb1 + hw] = u;
  }
  sum0 += __shfl_xor(sum0, 32, 64);
  sum1 += __shfl_xor(sum1, 32, 64);
  if (lane < 32) {
    atomicAdd(&a_sum[n * 64 + l31], sum0);
    atomicAdd(&a_sum[n * 64 + 32 + l31], sum1);
  }
}

// ---------------- Kernel B: v = xt @ a^T + a_sum*C -> out, fused ssq -------
// grid (8 d-tiles, 64 images), 256 thr / 4 waves. Wave: 32d x 32k.
__global__ __launch_bounds__(256) void kvlad(
    const unsigned short* __restrict__ xt, const unsigned short* __restrict__ at,
    const float* __restrict__ a_sum, const float* __restrict__ C,
    float* __restrict__ out, float* __restrict__ ssq) {
  __shared__ unsigned short xa[64][72];    // [d][hw-chunk]
  __shared__ unsigned short as_[64][72];   // [k][hw-chunk]
  const int t = threadIdx.x;
  const int w = t >> 6, lane = t & 63, l31 = lane & 31, h = lane >> 5;
  const int n = blockIdx.y, d0 = blockIdx.x * 64;
  const int dw = 32 * (w & 1), kw = 32 * (w >> 1);
  const int sd = t >> 2, sseg = (t & 3) * 16;  // stage maps (both operands)
  const size_t xbase = ((size_t)n * 512 + d0 + sd) * 1024;
  const size_t abase = ((size_t)n * 64 + sd) * 1024;

  uint4 px0, px1, pa0, pa1;
  px0 = *(const uint4*)&xt[xbase + sseg];
  px1 = *(const uint4*)&xt[xbase + sseg + 8];
  pa0 = *(const uint4*)&at[abase + sseg];
  pa1 = *(const uint4*)&at[abase + sseg + 8];

  f32x16 acc;
#pragma unroll
  for (int i = 0; i < 16; ++i) acc[i] = 0.f;

  for (int c = 0; c < 16; ++c) {
    __syncthreads();
    *(uint4*)&xa[sd][sseg] = px0;
    *(uint4*)&xa[sd][sseg + 8] = px1;
    *(uint4*)&as_[sd][sseg] = pa0;
    *(uint4*)&as_[sd][sseg + 8] = pa1;
    __syncthreads();
    if (c < 15) {
      const int hw0 = (c + 1) * 64;
      px0 = *(const uint4*)&xt[xbase + hw0 + sseg];
      px1 = *(const uint4*)&xt[xbase + hw0 + sseg + 8];
      pa0 = *(const uint4*)&at[abase + hw0 + sseg];
      pa1 = *(const uint4*)&at[abase + hw0 + sseg + 8];
    }
#pragma unroll
    for (int s = 0; s < 4; ++s) {
      int kk = s * 16 + h * 8;
      bf16x8 ax = *(const bf16x8*)&xa[dw + l31][kk];
      bf16x8 bb = *(const bf16x8*)&as_[kw + l31][kk];
      acc = __builtin_amdgcn_mfma_f32_32x32x16_bf16(ax, bb, acc, 0, 0, 0);
    }
  }

  const int k = kw + l31;
  const float as = a_sum[n * 64 + k];
  float sq = 0.f;
#pragma unroll
  for (int r = 0; r < 16; ++r) {
    int row = (r & 3) + 8 * (r >> 2) + 4 * h;
    int d = d0 + dw + row;
    float o = acc[r] + as * C[(size_t)d * 64 + k];
    out[((size_t)n * 512 + d) * 64 + k] = o;
    sq += o * o;
  }
  atomicAdd(&ssq[n * 64 + k], sq);
}

// ---------------- C: scale in place ----------------
__global__ __launch_bounds__(256) void kscale(
    float* __restrict__ out, const float* __restrict__ ssq) {
  const int n = blockIdx.y, slice = blockIdx.x;
  const int t = threadIdx.x, k = t & 63, rg = t >> 6;
  __shared__ float sk[64];
  __shared__ float tot;
  if (t < 64) {
    float c = ssq[n * 64 + t];
    sk[t] = rsqrtf(c + EPSF);
    float contrib = c / (c + EPSF);
#pragma unroll
    for (int m = 32; m; m >>= 1) contrib += __shfl_xor(contrib, m, 64);
    if (t == 0) tot = rsqrtf(contrib + EPSF);
  }
  __syncthreads();
  const float scale = sk[k] * tot;
  float* vb = out + (size_t)n * 32768 + (size_t)slice * 4096;
#pragma unroll
  for (int r = rg; r < 64; r += 4) vb[r * 64 + k] *= scale;
}

extern "C" void kernel_launch(void* const* d_in, const int* in_sizes, int n_in,
                              void* d_out, int out_size, void* d_ws, size_t ws_size,
                              hipStream_t stream) {
  const float* x  = (const float*)d_in[0];   // [64,32,32,512]
  const float* Wm = (const float*)d_in[1];   // [512,64]
  const float* b  = (const float*)d_in[2];   // [64]
  const float* C  = (const float*)d_in[3];   // [512,64]
  float* out = (float*)d_out;                // [64, 32768]

  unsigned short* at = (unsigned short*)d_ws;          // 8 MiB  [n*64+k][1024]
  unsigned short* xt = at + (size_t)64 * 64 * 1024;    // 64 MiB [n][512 d][1024 hw]
  unsigned short* wt = xt + (size_t)64 * 512 * 1024;   // 64 KiB [k][512 d]
  float* a_sum = (float*)(wt + (size_t)64 * 512);      // 16 KiB
  float* ssq   = a_sum + 4096;                         // 16 KiB

  hipMemsetAsync(a_sum, 0, 8192 * sizeof(float), stream);  // a_sum + ssq
  kprep<<<dim3(8), dim3(256), 0, stream>>>(Wm, wt);
  kassign<<<dim3(512), dim3(256), 0, stream>>>(x, wt, b, at, xt, a_sum);
  kvlad<<<dim3(8, 64), dim3(256), 0, stream>>>(xt, at, a_sum, C, out, ssq);
  kscale<<<dim3(8, 64), dim3(256), 0, stream>>>(out, ssq);
}